// Round 4
// baseline (129.240 us; speedup 1.0000x reference)
//
#include <hip/hip_runtime.h>

// MLPScorer: out[b,t,s] = sum_d v[d] * tanh( (h_t Wq^T + bq)[b,t,d] + (h_s Wc^T)[b,s,d] )
// B=4, T=S=D=512, all f32.
//
// tanh(x) = 1 - 2/(1+e^{2x});  e^{2(a+u)} = ea*eu (separable; precomputed in the
// GEMM epilogue as exp2(c*...), c = 2*log2(e)).
// Scorer groups 4 consecutive d per output (1 rcp / 4 elements):
//   F_i = fma(ea_i, eu_i, 1);  sum_i v_i/F_i = num/den,
//   num = (v0*F1+v1*F0)*F2*F3 + (v2*F3+v3*F2)*F0*F1, den = F0*F1*F2*F3.
// out = sumv - 2*acc.

#define B_ 4
#define T_ 512
#define S_ 512
#define D_ 512

static constexpr float C2LOG2E = 2.8853900817779268f; // 2*log2(e)

// ---------------------------------------------------------------------------
// Dual GEMM + exp2 epilogue, both jobs Out = X * W^T (K = 512):
//  job0: X=h_t [2048][512], W=Wq  [512][512] -> Ea [2048][512] (+bq), natural layout
//  job1: X=Wc  [512][512],  W=h_s [2048][512] -> Eu4, d-interleaved:
//        Eu4[ ((d>>2)*2048 + col)*4 + (d&3) ], col = b*S+s
//        (thread's 4x4 micro-tile transposed in registers -> 4 coalesced float4)
// ---------------------------------------------------------------------------
__global__ __launch_bounds__(256) void gemm_exp_kernel(
    const float* __restrict__ Ht, const float* __restrict__ Hs,
    const float* __restrict__ Wq, const float* __restrict__ bq,
    const float* __restrict__ Wc,
    float* __restrict__ Ea, float* __restrict__ Eu4)
{
    __shared__ float Xs[32][68];   // [k][row]
    __shared__ float Ws[32][68];   // [k][col]
    const int job = blockIdx.z;
    const float* __restrict__ X = job ? Wc : Ht;
    const float* __restrict__ W = job ? Hs : Wq;
    const int r0 = (job ? blockIdx.y : blockIdx.x) * 64;   // X-row block
    const int e0 = (job ? blockIdx.x : blockIdx.y) * 64;   // W-row (out col) block

    const int tid = threadIdx.x;
    const int tx  = tid & 15;      // col group (4 cols)
    const int ty  = tid >> 4;      // row group (4 rows)
    const int li  = tid >> 3;          // 0..31 staging row
    const int lk  = (tid & 7) << 2;    // 0,4,...,28 staging k

    float acc[4][4] = {{0.f,0.f,0.f,0.f},{0.f,0.f,0.f,0.f},
                       {0.f,0.f,0.f,0.f},{0.f,0.f,0.f,0.f}};

    for (int k0 = 0; k0 < D_; k0 += 32) {
        const float4 x0 = *(const float4*)(X + (size_t)(r0 + li)      * D_ + k0 + lk);
        const float4 x1 = *(const float4*)(X + (size_t)(r0 + li + 32) * D_ + k0 + lk);
        const float4 w0 = *(const float4*)(W + (size_t)(e0 + li)      * D_ + k0 + lk);
        const float4 w1 = *(const float4*)(W + (size_t)(e0 + li + 32) * D_ + k0 + lk);
        __syncthreads();   // protect previous chunk's LDS reads
        Xs[lk+0][li] = x0.x; Xs[lk+1][li] = x0.y; Xs[lk+2][li] = x0.z; Xs[lk+3][li] = x0.w;
        Xs[lk+0][li+32] = x1.x; Xs[lk+1][li+32] = x1.y; Xs[lk+2][li+32] = x1.z; Xs[lk+3][li+32] = x1.w;
        Ws[lk+0][li] = w0.x; Ws[lk+1][li] = w0.y; Ws[lk+2][li] = w0.z; Ws[lk+3][li] = w0.w;
        Ws[lk+0][li+32] = w1.x; Ws[lk+1][li+32] = w1.y; Ws[lk+2][li+32] = w1.z; Ws[lk+3][li+32] = w1.w;
        __syncthreads();
#pragma unroll
        for (int k = 0; k < 32; ++k) {
            const float4 a  = *(const float4*)&Xs[k][ty << 2];
            const float4 bb = *(const float4*)&Ws[k][tx << 2];
            acc[0][0] = fmaf(a.x, bb.x, acc[0][0]);
            acc[0][1] = fmaf(a.x, bb.y, acc[0][1]);
            acc[0][2] = fmaf(a.x, bb.z, acc[0][2]);
            acc[0][3] = fmaf(a.x, bb.w, acc[0][3]);
            acc[1][0] = fmaf(a.y, bb.x, acc[1][0]);
            acc[1][1] = fmaf(a.y, bb.y, acc[1][1]);
            acc[1][2] = fmaf(a.y, bb.z, acc[1][2]);
            acc[1][3] = fmaf(a.y, bb.w, acc[1][3]);
            acc[2][0] = fmaf(a.z, bb.x, acc[2][0]);
            acc[2][1] = fmaf(a.z, bb.y, acc[2][1]);
            acc[2][2] = fmaf(a.z, bb.z, acc[2][2]);
            acc[2][3] = fmaf(a.z, bb.w, acc[2][3]);
            acc[3][0] = fmaf(a.w, bb.x, acc[3][0]);
            acc[3][1] = fmaf(a.w, bb.y, acc[3][1]);
            acc[3][2] = fmaf(a.w, bb.z, acc[3][2]);
            acc[3][3] = fmaf(a.w, bb.w, acc[3][3]);
        }
    }

    if (!job) {
        const float4 bv = *(const float4*)(bq + e0 + (tx << 2));
#pragma unroll
        for (int i = 0; i < 4; ++i) {
            float4 o;
            o.x = __builtin_amdgcn_exp2f(C2LOG2E * (acc[i][0] + bv.x));
            o.y = __builtin_amdgcn_exp2f(C2LOG2E * (acc[i][1] + bv.y));
            o.z = __builtin_amdgcn_exp2f(C2LOG2E * (acc[i][2] + bv.z));
            o.w = __builtin_amdgcn_exp2f(C2LOG2E * (acc[i][3] + bv.w));
            *(float4*)(Ea + (size_t)(r0 + (ty << 2) + i) * 512 + e0 + (tx << 2)) = o;
        }
    } else {
        // rows are d, cols are b*S+s. (row>>2) = r0/4 + ty, (row&3) = i.
        float* base = Eu4 + ((size_t)((r0 >> 2) + ty) * 2048 + e0 + (tx << 2)) * 4;
#pragma unroll
        for (int j = 0; j < 4; ++j) {
            float4 o;   // transposed: d-index varies inside the float4
            o.x = __builtin_amdgcn_exp2f(C2LOG2E * acc[0][j]);
            o.y = __builtin_amdgcn_exp2f(C2LOG2E * acc[1][j]);
            o.z = __builtin_amdgcn_exp2f(C2LOG2E * acc[2][j]);
            o.w = __builtin_amdgcn_exp2f(C2LOG2E * acc[3][j]);
            *(float4*)(base + (j << 2)) = o;
        }
    }
}

// ---------------------------------------------------------------------------
// Scorer, LDS-free. Wave: 2 t x 64 s (lane = s). Per d-group of 4:
// one coalesced dwordx4 of Eu4, uniform float4 of Ea(x2) and v.
// 1-D grid 2048, XCD-decode: id%8 -> (b, t-half) so each XCD's working set
// (Ea half-slice 512KB + Eu b-slice 1MB) fits its 4MB L2.
// ---------------------------------------------------------------------------
__device__ __forceinline__ float grp4(float ax, float ay, float az, float aw,
                                      float4 u, float4 vv, float acc)
{
    const float F0 = fmaf(ax, u.x, 1.0f);
    const float F1 = fmaf(ay, u.y, 1.0f);
    const float F2 = fmaf(az, u.z, 1.0f);
    const float F3 = fmaf(aw, u.w, 1.0f);
    const float g   = F0 * F1;
    const float h   = F2 * F3;
    const float n01 = fmaf(vv.y, F0, vv.x * F1);
    const float n23 = fmaf(vv.w, F2, vv.z * F3);
    const float num = fmaf(n23, g, n01 * h);
    const float den = g * h;
    return fmaf(num, __builtin_amdgcn_rcpf(den), acc);
}

__global__ __launch_bounds__(256, 8) void score_kernel(
    const float* __restrict__ Ea,   // [B*T][512]
    const float* __restrict__ Eu4,  // [(512/4)][2048][4]
    const float* __restrict__ v, float* __restrict__ out)
{
    const int lane = threadIdx.x & 63;
    const int w    = threadIdx.x >> 6;
    const int f    = blockIdx.x;
    const int gg   = f & 7;          // XCD group: (b, t-half)
    const int k    = f >> 3;         // 0..255 within group
    const int b    = gg >> 1;
    const int thalf= gg & 1;
    const int sblk = k & 7;          // 8 s-blocks
    const int tblk = k >> 3;         // 32 t-blocks (of 8 rows) per half
    const int t0   = (thalf << 8) + (tblk << 3) + (w << 1);
    const int s    = (sblk << 6) + lane;

    // sumv = sum_d v[d], butterfly (all lanes get it)
    float p = 0.f;
#pragma unroll
    for (int q = 0; q < 8; ++q) p += v[lane + (q << 6)];
#pragma unroll
    for (int off = 32; off; off >>= 1) p += __shfl_xor(p, off);
    const float sumv = p;

    const float* __restrict__ A0 = Ea + (size_t)(b * T_ + t0) * D_;
    const float* __restrict__ A1 = A0 + D_;
    const float* __restrict__ U  = Eu4 + ((size_t)b * S_ + s) * 4;  // +32KB per d-group

    float acc0 = 0.f, acc1 = 0.f;

#pragma unroll 2
    for (int dg = 0; dg < 128; ++dg) {
        const float4 u  = *(const float4*)(U + (size_t)dg * 8192);
        const float4 vv = *(const float4*)(v + (dg << 2));
        const float4 a0 = *(const float4*)(A0 + (dg << 2));
        const float4 a1 = *(const float4*)(A1 + (dg << 2));
        acc0 = grp4(a0.x, a0.y, a0.z, a0.w, u, vv, acc0);
        acc1 = grp4(a1.x, a1.y, a1.z, a1.w, u, vv, acc1);
    }

    float* __restrict__ O = out + (size_t)(b * T_ + t0) * S_ + s;
    O[0]  = sumv - 2.0f * acc0;
    O[S_] = sumv - 2.0f * acc1;
}

extern "C" void kernel_launch(void* const* d_in, const int* in_sizes, int n_in,
                              void* d_out, int out_size, void* d_ws, size_t ws_size,
                              hipStream_t stream) {
    const float* h_t = (const float*)d_in[0];  // [4,512,512]
    const float* h_s = (const float*)d_in[1];  // [4,512,512]
    const float* Wq  = (const float*)d_in[2];  // [512,512]
    const float* bq  = (const float*)d_in[3];  // [512]
    const float* Wc  = (const float*)d_in[4];  // [512,512]
    const float* v   = (const float*)d_in[5];  // [512]
    float* out = (float*)d_out;                // [4,512,512]

    float* Ea  = (float*)d_ws;                 // exp2(c*(h_t Wq^T + bq)) [2048][512]
    float* Eu4 = Ea + (size_t)B_ * T_ * D_;    // exp2(c*(h_s Wc^T)), d-interleaved

    gemm_exp_kernel<<<dim3(32, 8, 2), 256, 0, stream>>>(h_t, h_s, Wq, bq, Wc, Ea, Eu4);
    score_kernel<<<dim3(2048, 1, 1), 256, 0, stream>>>(Ea, Eu4, v, out);
}

// Round 5
// 97.749 us; speedup vs baseline: 1.3222x; 1.3222x over previous
//
#include <hip/hip_runtime.h>

// MLPScorer: out[b,t,s] = sum_d v[d] * tanh( (h_t Wq^T + bq)[b,t,d] + (h_s Wc^T)[b,s,d] )
// B=4, T=S=D=512, all f32.
//
// tanh(x) = 1 - 2/(1+e^{2x});  e^{2(a+u)} = ea*eu (separable; precomputed in the
// GEMM epilogue as exp2(c*...), c = 2*log2(e)).
// Scorer groups 4 consecutive d per output (1 rcp / 4 elements):
//   F_i = fma(ea_i, eu_i, 1);  sum_i v_i/F_i = num/den,
//   num = (v0*F1+v1*F0)*F2*F3 + (v2*F3+v3*F2)*F0*F1, den = F0*F1*F2*F3.
// out = sumv - 2*acc.

#define B_ 4
#define T_ 512
#define S_ 512
#define D_ 512

static constexpr float C2LOG2E = 2.8853900817779268f; // 2*log2(e)

// ---------------------------------------------------------------------------
// Dual GEMM + exp2 epilogue, both jobs Out = X * W^T (K = 512):
//  job0: X=h_t [2048][512], W=Wq  [512][512] -> Ea [2048][512] (+bq), natural layout
//  job1: X=Wc  [512][512],  W=h_s [2048][512] -> Eu4, d-interleaved:
//        Eu4[ ((d>>2)*2048 + col)*4 + (d&3) ], col = b*S+s
// ---------------------------------------------------------------------------
__global__ __launch_bounds__(256) void gemm_exp_kernel(
    const float* __restrict__ Ht, const float* __restrict__ Hs,
    const float* __restrict__ Wq, const float* __restrict__ bq,
    const float* __restrict__ Wc,
    float* __restrict__ Ea, float* __restrict__ Eu4)
{
    __shared__ float Xs[32][68];   // [k][row]
    __shared__ float Ws[32][68];   // [k][col]
    const int job = blockIdx.z;
    const float* __restrict__ X = job ? Wc : Ht;
    const float* __restrict__ W = job ? Hs : Wq;
    const int r0 = (job ? blockIdx.y : blockIdx.x) * 64;   // X-row block
    const int e0 = (job ? blockIdx.x : blockIdx.y) * 64;   // W-row (out col) block

    const int tid = threadIdx.x;
    const int tx  = tid & 15;      // col group (4 cols)
    const int ty  = tid >> 4;      // row group (4 rows)
    const int li  = tid >> 3;          // 0..31 staging row
    const int lk  = (tid & 7) << 2;    // 0,4,...,28 staging k

    float acc[4][4] = {{0.f,0.f,0.f,0.f},{0.f,0.f,0.f,0.f},
                       {0.f,0.f,0.f,0.f},{0.f,0.f,0.f,0.f}};

    for (int k0 = 0; k0 < D_; k0 += 32) {
        const float4 x0 = *(const float4*)(X + (size_t)(r0 + li)      * D_ + k0 + lk);
        const float4 x1 = *(const float4*)(X + (size_t)(r0 + li + 32) * D_ + k0 + lk);
        const float4 w0 = *(const float4*)(W + (size_t)(e0 + li)      * D_ + k0 + lk);
        const float4 w1 = *(const float4*)(W + (size_t)(e0 + li + 32) * D_ + k0 + lk);
        __syncthreads();   // protect previous chunk's LDS reads
        Xs[lk+0][li] = x0.x; Xs[lk+1][li] = x0.y; Xs[lk+2][li] = x0.z; Xs[lk+3][li] = x0.w;
        Xs[lk+0][li+32] = x1.x; Xs[lk+1][li+32] = x1.y; Xs[lk+2][li+32] = x1.z; Xs[lk+3][li+32] = x1.w;
        Ws[lk+0][li] = w0.x; Ws[lk+1][li] = w0.y; Ws[lk+2][li] = w0.z; Ws[lk+3][li] = w0.w;
        Ws[lk+0][li+32] = w1.x; Ws[lk+1][li+32] = w1.y; Ws[lk+2][li+32] = w1.z; Ws[lk+3][li+32] = w1.w;
        __syncthreads();
#pragma unroll
        for (int k = 0; k < 32; ++k) {
            const float4 a  = *(const float4*)&Xs[k][ty << 2];
            const float4 bb = *(const float4*)&Ws[k][tx << 2];
            acc[0][0] = fmaf(a.x, bb.x, acc[0][0]);
            acc[0][1] = fmaf(a.x, bb.y, acc[0][1]);
            acc[0][2] = fmaf(a.x, bb.z, acc[0][2]);
            acc[0][3] = fmaf(a.x, bb.w, acc[0][3]);
            acc[1][0] = fmaf(a.y, bb.x, acc[1][0]);
            acc[1][1] = fmaf(a.y, bb.y, acc[1][1]);
            acc[1][2] = fmaf(a.y, bb.z, acc[1][2]);
            acc[1][3] = fmaf(a.y, bb.w, acc[1][3]);
            acc[2][0] = fmaf(a.z, bb.x, acc[2][0]);
            acc[2][1] = fmaf(a.z, bb.y, acc[2][1]);
            acc[2][2] = fmaf(a.z, bb.z, acc[2][2]);
            acc[2][3] = fmaf(a.z, bb.w, acc[2][3]);
            acc[3][0] = fmaf(a.w, bb.x, acc[3][0]);
            acc[3][1] = fmaf(a.w, bb.y, acc[3][1]);
            acc[3][2] = fmaf(a.w, bb.z, acc[3][2]);
            acc[3][3] = fmaf(a.w, bb.w, acc[3][3]);
        }
    }

    if (!job) {
        const float4 bv = *(const float4*)(bq + e0 + (tx << 2));
#pragma unroll
        for (int i = 0; i < 4; ++i) {
            float4 o;
            o.x = __builtin_amdgcn_exp2f(C2LOG2E * (acc[i][0] + bv.x));
            o.y = __builtin_amdgcn_exp2f(C2LOG2E * (acc[i][1] + bv.y));
            o.z = __builtin_amdgcn_exp2f(C2LOG2E * (acc[i][2] + bv.z));
            o.w = __builtin_amdgcn_exp2f(C2LOG2E * (acc[i][3] + bv.w));
            *(float4*)(Ea + (size_t)(r0 + (ty << 2) + i) * 512 + e0 + (tx << 2)) = o;
        }
    } else {
        // rows are d, cols are b*S+s. (row>>2) = r0/4 + ty, (row&3) = i.
        float* base = Eu4 + ((size_t)((r0 >> 2) + ty) * 2048 + e0 + (tx << 2)) * 4;
#pragma unroll
        for (int j = 0; j < 4; ++j) {
            float4 o;   // transposed: d-index varies inside the float4
            o.x = __builtin_amdgcn_exp2f(C2LOG2E * acc[0][j]);
            o.y = __builtin_amdgcn_exp2f(C2LOG2E * acc[1][j]);
            o.z = __builtin_amdgcn_exp2f(C2LOG2E * acc[2][j]);
            o.w = __builtin_amdgcn_exp2f(C2LOG2E * acc[3][j]);
            *(float4*)(base + (j << 2)) = o;
        }
    }
}

// ---------------------------------------------------------------------------
// Scorer. Block = 4 waves, tile 4t x 256s (each wave: 4t x 64s, lane = s).
// A-tile (4 rows x 512 d = 8KB) + v (2KB) staged in LDS once -> main loop's
// only VMEM is the per-lane coalesced Eu4 dwordx4 (1KB/wave-iter); uniform
// operands come from the LDS pipe (broadcast, conflict-free), parallel to
// VMEM and VALU. No barriers in the main loop.
// 1-D grid 1024, XCD decode: id%8 = (b, s-half) -> per-XCD L2 working set
// Eu4 slice 512KB + Ea b-slice 1MB.
// ---------------------------------------------------------------------------
__device__ __forceinline__ float grp4(float ax, float ay, float az, float aw,
                                      float4 u, float4 vv, float acc)
{
    const float F0 = fmaf(ax, u.x, 1.0f);
    const float F1 = fmaf(ay, u.y, 1.0f);
    const float F2 = fmaf(az, u.z, 1.0f);
    const float F3 = fmaf(aw, u.w, 1.0f);
    const float g   = F0 * F1;
    const float h   = F2 * F3;
    const float n01 = fmaf(vv.y, F0, vv.x * F1);
    const float n23 = fmaf(vv.w, F2, vv.z * F3);
    const float num = fmaf(n23, g, n01 * h);
    const float den = g * h;
    return fmaf(num, __builtin_amdgcn_rcpf(den), acc);
}

__global__ __launch_bounds__(256, 4) void score_kernel(
    const float* __restrict__ Ea,   // [B*T][512]
    const float* __restrict__ Eu4,  // [(512/4)][2048][4]
    const float* __restrict__ v, float* __restrict__ out)
{
    __shared__ float As[4][512];    // A-tile: 4 t-rows
    __shared__ float vs[512];
    const int tid  = threadIdx.x;
    const int lane = tid & 63;
    const int w    = tid >> 6;
    const int id   = blockIdx.x;
    const int gg   = id & 7;         // XCD group: (b, s-half)
    const int b    = gg >> 1;
    const int shlf = gg & 1;
    const int tblk = id >> 3;        // 0..127
    const int t0   = tblk << 2;
    const int s    = (shlf << 8) + (w << 6) + lane;

    // sumv = sum_d v[d], butterfly (all lanes get it)
    float p = 0.f;
#pragma unroll
    for (int q = 0; q < 8; ++q) p += v[lane + (q << 6)];
#pragma unroll
    for (int off = 32; off; off >>= 1) p += __shfl_xor(p, off);
    const float sumv = p;

    // Stage A-tile (2048 floats) + v (512 floats) into LDS
    {
        const float* Arow = Ea + (size_t)(b * T_ + t0) * D_;  // 4 consecutive rows
        float* Af = &As[0][0];
        *(float4*)(Af + (tid << 2))        = *(const float4*)(Arow + (tid << 2));
        *(float4*)(Af + (tid << 2) + 1024) = *(const float4*)(Arow + (tid << 2) + 1024);
        if (tid < 128) *(float4*)(vs + (tid << 2)) = *(const float4*)(v + (tid << 2));
    }
    __syncthreads();

    const float* __restrict__ U = Eu4 + ((size_t)b * S_ + s) * 4;  // +32KB per d-group
    float acc0 = 0.f, acc1 = 0.f, acc2 = 0.f, acc3 = 0.f;

#pragma unroll 2
    for (int dg = 0; dg < 128; ++dg) {
        const float4 u  = *(const float4*)(U + (size_t)dg * 8192);
        const float4 vv = *(const float4*)&vs[dg << 2];
        const float4 a0 = *(const float4*)&As[0][dg << 2];
        const float4 a1 = *(const float4*)&As[1][dg << 2];
        const float4 a2 = *(const float4*)&As[2][dg << 2];
        const float4 a3 = *(const float4*)&As[3][dg << 2];
        acc0 = grp4(a0.x, a0.y, a0.z, a0.w, u, vv, acc0);
        acc1 = grp4(a1.x, a1.y, a1.z, a1.w, u, vv, acc1);
        acc2 = grp4(a2.x, a2.y, a2.z, a2.w, u, vv, acc2);
        acc3 = grp4(a3.x, a3.y, a3.z, a3.w, u, vv, acc3);
    }

    float* __restrict__ O = out + (size_t)(b * T_ + t0) * S_ + s;
    O[0 * S_] = sumv - 2.0f * acc0;
    O[1 * S_] = sumv - 2.0f * acc1;
    O[2 * S_] = sumv - 2.0f * acc2;
    O[3 * S_] = sumv - 2.0f * acc3;
}

extern "C" void kernel_launch(void* const* d_in, const int* in_sizes, int n_in,
                              void* d_out, int out_size, void* d_ws, size_t ws_size,
                              hipStream_t stream) {
    const float* h_t = (const float*)d_in[0];  // [4,512,512]
    const float* h_s = (const float*)d_in[1];  // [4,512,512]
    const float* Wq  = (const float*)d_in[2];  // [512,512]
    const float* bq  = (const float*)d_in[3];  // [512]
    const float* Wc  = (const float*)d_in[4];  // [512,512]
    const float* v   = (const float*)d_in[5];  // [512]
    float* out = (float*)d_out;                // [4,512,512]

    float* Ea  = (float*)d_ws;                 // exp2(c*(h_t Wq^T + bq)) [2048][512]
    float* Eu4 = Ea + (size_t)B_ * T_ * D_;    // exp2(c*(h_s Wc^T)), d-interleaved

    gemm_exp_kernel<<<dim3(32, 8, 2), 256, 0, stream>>>(h_t, h_s, Wq, bq, Wc, Ea, Eu4);
    score_kernel<<<dim3(1024, 1, 1), 256, 0, stream>>>(Ea, Eu4, v, out);
}